// Round 11
// baseline (51.506 us; speedup 1.0000x reference)
//
#include <hip/hip_runtime.h>
#include <hip/hip_cooperative_groups.h>

namespace cg = cooperative_groups;

#define IMG   512
#define NCLS  256
#define DIM   1024
#define HPW   32
#define TPB   8            // tokens per block (MFMA rows 8..15 zero)
#define NT    1024         // 16 waves; wave owns 64 dims

typedef short bf16x8 __attribute__((ext_vector_type(8)));
typedef float f32x4  __attribute__((ext_vector_type(4)));

__device__ inline ushort bf16rne(float v) {
    unsigned u = __float_as_uint(v);
    return (ushort)((u + 0x7fffu + ((u >> 16) & 1u)) >> 16);
}

// Single cooperative kernel.  Assumes grid = 256 blocks (2048 tokens / 8).
// Phase A (per block): pack 1/4 dtile of table into fragment-ordered bf16 Tt2
//   Tt2[dtile*4096 + ks*512 + g*128 + c*8 + j] = bf16(table[ks*32+g*8+j][dtile*16+c])
//   + block-local histogram of its 8 patches.
// grid.sync()
// Phase B: MFMA GEMM (8 tok x 1024 dim x 256 cls) + sincos pos + LN + store.
__global__ __launch_bounds__(NT)
void fused_coop(const int* __restrict__ smap, const float* __restrict__ table,
                const float* __restrict__ gamma, const float* __restrict__ beta,
                float* __restrict__ out, ushort* __restrict__ Tt2)
{
    __shared__ unsigned cnt[TPB * NCLS];      // 8 KB
    __shared__ ushort   cntb[16][264];        // rows 8..15 stay zero; stride 528 B
    __shared__ ushort   tile[16][72];         // pack staging: [dim-in-tile][class-local]
    __shared__ float    red[16][2][4][2];     // [wave][g][i][{s,s2}]

    const int t    = threadIdx.x;
    const int lane = t & 63;
    const int w    = t >> 6;                  // 16 waves; wave owns dims [w*64, w*64+64)
    const int c    = lane & 15;
    const int g    = lane >> 4;

    const int bid  = blockIdx.x;
    const int tok0 = bid * TPB;
    const int b    = tok0 >> 10;
    const int ph   = (tok0 >> 5) & 31;
    const int pw0  = tok0 & 31;

    const int dtile = bid >> 2;               // 0..63
    const int cq    = bid & 3;                // class quarter (64 classes)

    // ---- zero hist buffers ----
    for (int i = t; i < TPB * NCLS; i += NT) cnt[i] = 0u;
    for (int i = t; i < 16 * 264; i += NT) (&cntb[0][0])[i] = 0;

    // ---- pack load: 64 classes x 16 dims -> LDS tile (t < 256, float4 each) ----
    if (t < 256) {
        const int row = t >> 2, chunk = t & 3;            // class-local, dim-quad
        const float4 v = *reinterpret_cast<const float4*>(
            table + (size_t)(cq * 64 + row) * DIM + dtile * 16 + chunk * 4);
        tile[chunk * 4 + 0][row] = bf16rne(v.x);
        tile[chunk * 4 + 1][row] = bf16rne(v.y);
        tile[chunk * 4 + 2][row] = bf16rne(v.z);
        tile[chunk * 4 + 3][row] = bf16rne(v.w);
    }
    __syncthreads();

    // ---- pack write: contiguous 2 KB run, fully coalesced (1 ushort/thread) ----
    {
        const int cc = (t >> 3) & 15;                     // dim within dtile
        const int cl = ((t >> 9) << 5) | (((t >> 7) & 3) << 3) | (t & 7);  // class-local
        Tt2[(size_t)dtile * 4096 + cq * 1024 + t] = tile[cc][cl];
    }

    // ---- histogram: 8 patches = 16 rows x 128 cols, int2 per thread ----
    {
        const int p   = t * 2;
        const int row = p >> 7;               // 0..15
        const int col = p & 127;
        const int2 q = *reinterpret_cast<const int2*>(
            smap + ((size_t)b * IMG + (size_t)(ph * 16 + row)) * IMG + pw0 * 16 + col);
        unsigned* hp = &cnt[(col >> 4) * NCLS];
        atomicAdd(&hp[min(max(q.x, 0), NCLS - 1)], 1u);
        atomicAdd(&hp[min(max(q.y, 0), NCLS - 1)], 1u);
    }
    __syncthreads();

    // ---- counts -> bf16(count/256), exact (<=8 significant bits) ----
    for (int i = t; i < TPB * NCLS; i += NT)
        cntb[i >> 8][i & 255] = (ushort)(__float_as_uint((float)cnt[i] * (1.f / 256.f)) >> 16);

    // ---- grid-wide barrier: Tt2 visible to all XCDs ----
    cg::this_grid().sync();

    // ---- MFMA K-loop; A from LDS (broadcast b128), B = contiguous 1 KB wave-loads ----
    f32x4 acc[4];
    #pragma unroll
    for (int i = 0; i < 4; ++i) acc[i] = (f32x4){0.f, 0.f, 0.f, 0.f};

    const ushort* bt = Tt2 + (size_t)(w * 4) * 4096 + (size_t)lane * 8;
    #pragma unroll 2
    for (int ks = 0; ks < 8; ++ks) {
        const bf16x8 a = *reinterpret_cast<const bf16x8*>(&cntb[c][ks * 32 + g * 8]);
        bf16x8 bfv[4];
        #pragma unroll
        for (int nf = 0; nf < 4; ++nf)
            bfv[nf] = *reinterpret_cast<const bf16x8*>(bt + (size_t)nf * 4096 + ks * 512);
        #pragma unroll
        for (int nf = 0; nf < 4; ++nf)
            acc[nf] = __builtin_amdgcn_mfma_f32_16x16x32_bf16(a, bfv[nf], acc[nf], 0, 0, 0);
    }

    // ---- pos-embed + LN partials.  d = w*64 + nf*16 + c; D row r = g*4+i ----
    const int quad   = w >> 2;                // d>>8, wave-constant
    const int cosSel = quad & 1;
    float ls[4]  = {0, 0, 0, 0};
    float ls2[4] = {0, 0, 0, 0};

    #pragma unroll
    for (int nf = 0; nf < 4; ++nf) {
        const int dlow = (w & 3) * 64 + nf * 16 + c;      // d & 255
        const float omega = exp2f((float)dlow * (-13.287712379549449f / 256.f));
        if (quad < 2) {                       // h-embed: depends only on ph
            float sv, cv; __sincosf((float)ph * omega, &sv, &cv);
            const float v = cosSel ? cv : sv;
            #pragma unroll
            for (int i = 0; i < 4; ++i) acc[nf][i] += v;
        } else {                              // w-embed: pw = pw0 + g*4 + i (valid g<2)
            #pragma unroll
            for (int i = 0; i < 4; ++i) {
                float sv, cv; __sincosf((float)(pw0 + g * 4 + i) * omega, &sv, &cv);
                acc[nf][i] += cosSel ? cv : sv;
            }
        }
        #pragma unroll
        for (int i = 0; i < 4; ++i) { ls[i] += acc[nf][i]; ls2[i] += acc[nf][i] * acc[nf][i]; }
    }

    #pragma unroll
    for (int off = 1; off < 16; off <<= 1) {  // reduce over the 16 c-lanes (g preserved)
        #pragma unroll
        for (int i = 0; i < 4; ++i) {
            ls[i]  += __shfl_xor(ls[i],  off, 64);
            ls2[i] += __shfl_xor(ls2[i], off, 64);
        }
    }
    if (c == 0 && g < 2) {
        #pragma unroll
        for (int i = 0; i < 4; ++i) { red[w][g][i][0] = ls[i]; red[w][g][i][1] = ls2[i]; }
    }
    __syncthreads();

    // ---- finalize LN + store (valid rows r = g*4+i, g<2) ----
    if (g < 2) {
        float mu[4], rs[4];
        #pragma unroll
        for (int i = 0; i < 4; ++i) {
            float S = 0.f, S2 = 0.f;
            #pragma unroll
            for (int ww = 0; ww < 16; ++ww) { S += red[ww][g][i][0]; S2 += red[ww][g][i][1]; }
            mu[i] = S * (1.f / DIM);
            rs[i] = rsqrtf(S2 * (1.f / DIM) - mu[i] * mu[i] + 1e-5f);
        }
        #pragma unroll
        for (int nf = 0; nf < 4; ++nf) {
            const int d = w * 64 + nf * 16 + c;
            const float gv = gamma[d], bv = beta[d];
            #pragma unroll
            for (int i = 0; i < 4; ++i) {
                const int r = g * 4 + i;
                out[(size_t)(tok0 + r) * DIM + d] = (acc[nf][i] - mu[i]) * rs[i] * gv + bv;
            }
        }
    }
}

extern "C" void kernel_launch(void* const* d_in, const int* in_sizes, int n_in,
                              void* d_out, int out_size, void* d_ws, size_t ws_size,
                              hipStream_t stream) {
    const int*   smap  = (const int*)d_in[0];
    const float* table = (const float*)d_in[1];
    const float* gamma = (const float*)d_in[2];
    const float* beta  = (const float*)d_in[3];
    float*       out   = (float*)d_out;
    ushort*      Tt2   = (ushort*)d_ws;                  // 512 KB packed table

    const int batches = in_sizes[0] / (IMG * IMG);       // = 2
    const int tokens  = batches * HPW * HPW;             // 2048
    const int nblk    = tokens / TPB;                    // 256 (pack mapping assumes this)

    void* args[] = {(void*)&smap, (void*)&table, (void*)&gamma, (void*)&beta,
                    (void*)&out, (void*)&Tt2};
    hipLaunchCooperativeKernel((void*)fused_coop, dim3(nblk), dim3(NT), args, 0, stream);
}

// Round 12
// 21.868 us; speedup vs baseline: 2.3554x; 2.3554x over previous
//
#include <hip/hip_runtime.h>

#define IMG   512
#define NCLS  256
#define DIM   1024
#define HPW   32
#define TPB   8            // tokens per block (MFMA rows 8..15 zero)
#define NT2   1024         // 16 waves; wave owns 64 dims

typedef short bf16x8 __attribute__((ext_vector_type(8)));
typedef float f32x4  __attribute__((ext_vector_type(4)));

__device__ inline ushort bf16rne(float v) {
    unsigned u = __float_as_uint(v);
    return (ushort)((u + 0x7fffu + ((u >> 16) & 1u)) >> 16);
}

// ---------- K1: prep (320 blocks x 256 thr) ----------
// blocks [0,64):  pack table f32 [256 cls][1024 dim] -> fragment-ordered bf16 Tt2
//   Tt2[dtile*4096 + ks*512 + g*128 + c*8 + j] = bf16(table[ks*32+g*8+j][dtile*16+c])
// blocks [64,64+ngrp): histogram of token-group (8 patches) -> Ab bf16 [grp][16][256]
//   rows 0..7 = count/256 per patch, rows 8..15 = 0 (MFMA zero rows)
__global__ __launch_bounds__(256)
void prep(const int* __restrict__ smap, const float* __restrict__ table,
          ushort* __restrict__ Tt2, ushort* __restrict__ Ab)
{
    __shared__ ushort   tile[16][264];        // pack staging
    __shared__ unsigned cnt[TPB * NCLS];      // 8 KB hist
    const int t   = threadIdx.x;
    const int bid = blockIdx.x;

    if (bid < 64) {
        // ---- pack dtile = bid (verbatim R10 pack_table) ----
        const int dtile = bid;
        const int d0    = dtile * 16;
        {
            const float* src = table + (size_t)t * DIM + d0;
            #pragma unroll
            for (int q = 0; q < 4; ++q) {
                const float4 v = *reinterpret_cast<const float4*>(src + q * 4);
                tile[q * 4 + 0][t] = bf16rne(v.x);
                tile[q * 4 + 1][t] = bf16rne(v.y);
                tile[q * 4 + 2][t] = bf16rne(v.z);
                tile[q * 4 + 3][t] = bf16rne(v.w);
            }
        }
        __syncthreads();
        const int ks   = t >> 5;
        const int g    = (t >> 3) & 3;
        const int c0   = (t & 7) * 2;
        const int cls0 = ks * 32 + g * 8;
        uint4* dst = reinterpret_cast<uint4*>(Tt2 + (size_t)dtile * 4096 + (size_t)t * 16);
        dst[0] = *reinterpret_cast<const uint4*>(&tile[c0][cls0]);
        dst[1] = *reinterpret_cast<const uint4*>(&tile[c0 + 1][cls0]);
    } else {
        // ---- histogram for token group ----
        const int grp  = bid - 64;
        const int tok0 = grp * TPB;
        const int b    = tok0 >> 10;
        const int ph   = (tok0 >> 5) & 31;
        const int pw0  = tok0 & 31;

        #pragma unroll
        for (int i = t; i < TPB * NCLS; i += 256) cnt[i] = 0u;
        __syncthreads();

        // 8 patches = 16 rows x 128 cols; 8 px/thread (2x int4, same patch)
        {
            const int row = t >> 4;                       // 0..15
            const int col = (t & 15) * 8;                 // 0..120
            const int* bp = smap + ((size_t)b * IMG + (size_t)(ph * 16 + row)) * IMG
                                 + pw0 * 16 + col;
            const int4 q0 = *reinterpret_cast<const int4*>(bp);
            const int4 q1 = *reinterpret_cast<const int4*>(bp + 4);
            unsigned* hp = &cnt[(col >> 4) * NCLS];
            atomicAdd(&hp[min(max(q0.x, 0), NCLS - 1)], 1u);
            atomicAdd(&hp[min(max(q0.y, 0), NCLS - 1)], 1u);
            atomicAdd(&hp[min(max(q0.z, 0), NCLS - 1)], 1u);
            atomicAdd(&hp[min(max(q0.w, 0), NCLS - 1)], 1u);
            atomicAdd(&hp[min(max(q1.x, 0), NCLS - 1)], 1u);
            atomicAdd(&hp[min(max(q1.y, 0), NCLS - 1)], 1u);
            atomicAdd(&hp[min(max(q1.z, 0), NCLS - 1)], 1u);
            atomicAdd(&hp[min(max(q1.w, 0), NCLS - 1)], 1u);
        }
        __syncthreads();

        // counts -> bf16(count/256) (exact); rows 8..15 zero
        ushort* ab = Ab + (size_t)grp * 4096;
        #pragma unroll
        for (int i = t; i < 4096; i += 256) {
            ushort v = 0;
            if (i < TPB * NCLS)
                v = (ushort)(__float_as_uint((float)cnt[i] * (1.f / 256.f)) >> 16);
            ab[i] = v;
        }
    }
}

// ---------- K2: lean GEMM (8 tok x 1024 dim x 256 cls) + pos + LN -> out ----------
__global__ __launch_bounds__(NT2)      // no min-waves arg: natural 128-VGPR cap
void gemm_ln(const ushort* __restrict__ Ab, const ushort* __restrict__ Tt2,
             const float* __restrict__ gamma, const float* __restrict__ beta,
             float* __restrict__ out)
{
    __shared__ ushort cntb[16][264];          // padded: stride 528 B, conflict-free b128
    __shared__ float  red[16][2][4][2];       // [wave][g][i][{s,s2}]

    const int t    = threadIdx.x;
    const int lane = t & 63;
    const int w    = t >> 6;                  // 16 waves; wave owns dims [w*64, w*64+64)
    const int c    = lane & 15;
    const int g    = lane >> 4;

    const int tok0 = blockIdx.x * TPB;
    const int ph   = (tok0 >> 5) & 31;
    const int pw0  = tok0 & 31;

    // ---- load fragment-ready A (16x256 bf16, incl. zero rows) in one pass ----
    {
        const ushort4 v = reinterpret_cast<const ushort4*>(Ab + (size_t)blockIdx.x * 4096)[t];
        const int idx = t * 4;
        *reinterpret_cast<ushort4*>(&cntb[idx >> 8][idx & 255]) = v;
    }
    __syncthreads();

    // ---- MFMA K-loop; A from LDS (broadcast b128), B = contiguous 1 KB wave-loads ----
    f32x4 acc[4];
    #pragma unroll
    for (int i = 0; i < 4; ++i) acc[i] = (f32x4){0.f, 0.f, 0.f, 0.f};

    const ushort* bt = Tt2 + (size_t)(w * 4) * 4096 + (size_t)lane * 8;
    #pragma unroll 2
    for (int ks = 0; ks < 8; ++ks) {
        const bf16x8 a = *reinterpret_cast<const bf16x8*>(&cntb[c][ks * 32 + g * 8]);
        bf16x8 bfv[4];
        #pragma unroll
        for (int nf = 0; nf < 4; ++nf)
            bfv[nf] = *reinterpret_cast<const bf16x8*>(bt + (size_t)nf * 4096 + ks * 512);
        #pragma unroll
        for (int nf = 0; nf < 4; ++nf)
            acc[nf] = __builtin_amdgcn_mfma_f32_16x16x32_bf16(a, bfv[nf], acc[nf], 0, 0, 0);
    }

    // ---- pos-embed + LN partials.  d = w*64 + nf*16 + c; D row r = g*4+i ----
    const int quad   = w >> 2;                // d>>8, wave-constant
    const int cosSel = quad & 1;
    float ls[4]  = {0, 0, 0, 0};
    float ls2[4] = {0, 0, 0, 0};

    #pragma unroll
    for (int nf = 0; nf < 4; ++nf) {
        const int dlow = (w & 3) * 64 + nf * 16 + c;      // d & 255
        const float omega = exp2f((float)dlow * (-13.287712379549449f / 256.f));
        if (quad < 2) {                       // h-embed: depends only on ph
            float sv, cv; __sincosf((float)ph * omega, &sv, &cv);
            const float v = cosSel ? cv : sv;
            #pragma unroll
            for (int i = 0; i < 4; ++i) acc[nf][i] += v;
        } else {                              // w-embed: pw = pw0 + g*4 + i (valid g<2)
            #pragma unroll
            for (int i = 0; i < 4; ++i) {
                float sv, cv; __sincosf((float)(pw0 + g * 4 + i) * omega, &sv, &cv);
                acc[nf][i] += cosSel ? cv : sv;
            }
        }
        #pragma unroll
        for (int i = 0; i < 4; ++i) { ls[i] += acc[nf][i]; ls2[i] += acc[nf][i] * acc[nf][i]; }
    }

    #pragma unroll
    for (int off = 1; off < 16; off <<= 1) {  // reduce over the 16 c-lanes (g preserved)
        #pragma unroll
        for (int i = 0; i < 4; ++i) {
            ls[i]  += __shfl_xor(ls[i],  off, 64);
            ls2[i] += __shfl_xor(ls2[i], off, 64);
        }
    }
    if (c == 0 && g < 2) {
        #pragma unroll
        for (int i = 0; i < 4; ++i) { red[w][g][i][0] = ls[i]; red[w][g][i][1] = ls2[i]; }
    }
    __syncthreads();

    // ---- finalize LN + store (valid rows r = g*4+i, g<2) ----
    if (g < 2) {
        float mu[4], rs[4];
        #pragma unroll
        for (int i = 0; i < 4; ++i) {
            float S = 0.f, S2 = 0.f;
            #pragma unroll
            for (int ww = 0; ww < 16; ++ww) { S += red[ww][g][i][0]; S2 += red[ww][g][i][1]; }
            mu[i] = S * (1.f / DIM);
            rs[i] = rsqrtf(S2 * (1.f / DIM) - mu[i] * mu[i] + 1e-5f);
        }
        #pragma unroll
        for (int nf = 0; nf < 4; ++nf) {
            const int d = w * 64 + nf * 16 + c;
            const float gv = gamma[d], bv = beta[d];
            #pragma unroll
            for (int i = 0; i < 4; ++i) {
                const int r = g * 4 + i;
                out[(size_t)(tok0 + r) * DIM + d] = (acc[nf][i] - mu[i]) * rs[i] * gv + bv;
            }
        }
    }
}

extern "C" void kernel_launch(void* const* d_in, const int* in_sizes, int n_in,
                              void* d_out, int out_size, void* d_ws, size_t ws_size,
                              hipStream_t stream) {
    const int*   smap  = (const int*)d_in[0];
    const float* table = (const float*)d_in[1];
    const float* gamma = (const float*)d_in[2];
    const float* beta  = (const float*)d_in[3];
    float*       out   = (float*)d_out;

    const int batches = in_sizes[0] / (IMG * IMG);       // = 2
    const int tokens  = batches * HPW * HPW;             // 2048
    const int ngrp    = tokens / TPB;                    // 256

    ushort* Tt2 = (ushort*)d_ws;                         // 512 KB
    ushort* Ab  = Tt2 + (size_t)64 * 4096;               // 2 MB ([grp][16][256])

    prep<<<64 + ngrp, 256, 0, stream>>>(smap, table, Tt2, Ab);
    gemm_ln<<<ngrp, NT2, 0, stream>>>(Ab, Tt2, gamma, beta, out);
}

// Round 13
// 19.805 us; speedup vs baseline: 2.6007x; 1.1042x over previous
//
#include <hip/hip_runtime.h>

#define IMG   512
#define NCLS  256
#define DIM   1024
#define HPW   32
#define TPB   16           // tokens per block = full MFMA M (no zero rows)
#define NT2   1024         // 16 waves; wave owns 64 dims

typedef short bf16x8 __attribute__((ext_vector_type(8)));
typedef float f32x4  __attribute__((ext_vector_type(4)));

__device__ inline ushort bf16rne(float v) {
    unsigned u = __float_as_uint(v);
    return (ushort)((u + 0x7fffu + ((u >> 16) & 1u)) >> 16);
}

// ---------- K1: prep (64 + 128 blocks x 256 thr) ----------
// blocks [0,64):  pack table f32 [256 cls][1024 dim] -> fragment-ordered bf16 Tt2
//   Tt2[dtile*4096 + ks*512 + g*128 + c*8 + j] = bf16(table[ks*32+g*8+j][dtile*16+c])
// blocks [64,64+128): histogram of 16-token group -> Ab bf16 [grp][16][256]
__global__ __launch_bounds__(256)
void prep(const int* __restrict__ smap, const float* __restrict__ table,
          ushort* __restrict__ Tt2, ushort* __restrict__ Ab)
{
    __shared__ ushort   tile[16][264];        // pack staging
    __shared__ unsigned cnt[TPB * NCLS];      // 16 KB hist
    const int t   = threadIdx.x;
    const int bid = blockIdx.x;

    if (bid < 64) {
        // ---- pack dtile = bid (verbatim verified R10 pack_table) ----
        const int dtile = bid;
        const int d0    = dtile * 16;
        {
            const float* src = table + (size_t)t * DIM + d0;
            #pragma unroll
            for (int q = 0; q < 4; ++q) {
                const float4 v = *reinterpret_cast<const float4*>(src + q * 4);
                tile[q * 4 + 0][t] = bf16rne(v.x);
                tile[q * 4 + 1][t] = bf16rne(v.y);
                tile[q * 4 + 2][t] = bf16rne(v.z);
                tile[q * 4 + 3][t] = bf16rne(v.w);
            }
        }
        __syncthreads();
        const int ks   = t >> 5;
        const int g    = (t >> 3) & 3;
        const int c0   = (t & 7) * 2;
        const int cls0 = ks * 32 + g * 8;
        uint4* dst = reinterpret_cast<uint4*>(Tt2 + (size_t)dtile * 4096 + (size_t)t * 16);
        dst[0] = *reinterpret_cast<const uint4*>(&tile[c0][cls0]);
        dst[1] = *reinterpret_cast<const uint4*>(&tile[c0 + 1][cls0]);
    } else {
        // ---- histogram for 16-token group (16 patches, same patch-row) ----
        const int grp  = bid - 64;
        const int tok0 = grp * TPB;
        const int b    = tok0 >> 10;
        const int ph   = (tok0 >> 5) & 31;
        const int pw0  = tok0 & 31;           // 0 or 16

        #pragma unroll
        for (int i = t; i < TPB * NCLS; i += 256) cnt[i] = 0u;
        __syncthreads();

        // region: 16 rows x 256 cols = 4096 px; thread: 16 px of ONE patch (4x int4)
        {
            const int row = t >> 4;                       // 0..15
            const int p   = t & 15;                       // patch in group
            const int* bp = smap + ((size_t)b * IMG + (size_t)(ph * 16 + row)) * IMG
                                 + (pw0 + p) * 16;
            unsigned* hp = &cnt[p * NCLS];
            #pragma unroll
            for (int q4 = 0; q4 < 4; ++q4) {
                const int4 q = *reinterpret_cast<const int4*>(bp + q4 * 4);
                atomicAdd(&hp[min(max(q.x, 0), NCLS - 1)], 1u);
                atomicAdd(&hp[min(max(q.y, 0), NCLS - 1)], 1u);
                atomicAdd(&hp[min(max(q.z, 0), NCLS - 1)], 1u);
                atomicAdd(&hp[min(max(q.w, 0), NCLS - 1)], 1u);
            }
        }
        __syncthreads();

        // counts -> bf16(count/256) (exact, <=8 significant bits)
        ushort* ab = Ab + (size_t)grp * 4096;
        #pragma unroll
        for (int i = t; i < TPB * NCLS; i += 256)
            ab[i] = (ushort)(__float_as_uint((float)cnt[i] * (1.f / 256.f)) >> 16);
    }
}

// ---------- K2: GEMM (16 tok x 1024 dim x 256 cls) + pos + LN -> out ----------
__global__ __launch_bounds__(NT2)      // natural 128-VGPR cap
void gemm_ln(const ushort* __restrict__ Ab, const ushort* __restrict__ Tt2,
             const float* __restrict__ gamma, const float* __restrict__ beta,
             float* __restrict__ out)
{
    __shared__ ushort cntb[16][264];          // stride 528 B -> conflict-free b128
    __shared__ float  red[16][4][4][2];       // [wave][g][i][{s,s2}]

    const int t    = threadIdx.x;
    const int lane = t & 63;
    const int w    = t >> 6;                  // 16 waves; wave owns dims [w*64, w*64+64)
    const int c    = lane & 15;
    const int g    = lane >> 4;

    const int tok0 = blockIdx.x * TPB;
    const int ph   = (tok0 >> 5) & 31;
    const int pw0  = tok0 & 31;               // 0 or 16

    // ---- load fragment-ready A (16x256 bf16) in one coalesced pass ----
    {
        const ushort4 v = reinterpret_cast<const ushort4*>(Ab + (size_t)blockIdx.x * 4096)[t];
        const int idx = t * 4;
        *reinterpret_cast<ushort4*>(&cntb[idx >> 8][idx & 255]) = v;
    }
    __syncthreads();

    // ---- MFMA K-loop; A from LDS (broadcast b128), B = contiguous 1 KB wave-loads ----
    f32x4 acc[4];
    #pragma unroll
    for (int i = 0; i < 4; ++i) acc[i] = (f32x4){0.f, 0.f, 0.f, 0.f};

    const ushort* bt = Tt2 + (size_t)(w * 4) * 4096 + (size_t)lane * 8;
    #pragma unroll 2
    for (int ks = 0; ks < 8; ++ks) {
        const bf16x8 a = *reinterpret_cast<const bf16x8*>(&cntb[c][ks * 32 + g * 8]);
        bf16x8 bfv[4];
        #pragma unroll
        for (int nf = 0; nf < 4; ++nf)
            bfv[nf] = *reinterpret_cast<const bf16x8*>(bt + (size_t)nf * 4096 + ks * 512);
        #pragma unroll
        for (int nf = 0; nf < 4; ++nf)
            acc[nf] = __builtin_amdgcn_mfma_f32_16x16x32_bf16(a, bfv[nf], acc[nf], 0, 0, 0);
    }

    // ---- pos-embed + LN partials.  d = w*64 + nf*16 + c; D row r = g*4+i (token) ----
    const int quad   = w >> 2;                // d>>8, wave-constant
    const int cosSel = quad & 1;
    float ls[4]  = {0, 0, 0, 0};
    float ls2[4] = {0, 0, 0, 0};

    #pragma unroll
    for (int nf = 0; nf < 4; ++nf) {
        const int dlow = (w & 3) * 64 + nf * 16 + c;      // d & 255
        const float omega = exp2f((float)dlow * (-13.287712379549449f / 256.f));
        if (quad < 2) {                       // h-embed: depends only on ph
            float sv, cv; __sincosf((float)ph * omega, &sv, &cv);
            const float v = cosSel ? cv : sv;
            #pragma unroll
            for (int i = 0; i < 4; ++i) acc[nf][i] += v;
        } else {                              // w-embed: pw = pw0 + g*4 + i
            #pragma unroll
            for (int i = 0; i < 4; ++i) {
                float sv, cv; __sincosf((float)(pw0 + g * 4 + i) * omega, &sv, &cv);
                acc[nf][i] += cosSel ? cv : sv;
            }
        }
        #pragma unroll
        for (int i = 0; i < 4; ++i) { ls[i] += acc[nf][i]; ls2[i] += acc[nf][i] * acc[nf][i]; }
    }

    #pragma unroll
    for (int off = 1; off < 16; off <<= 1) {  // reduce over the 16 c-lanes (g preserved)
        #pragma unroll
        for (int i = 0; i < 4; ++i) {
            ls[i]  += __shfl_xor(ls[i],  off, 64);
            ls2[i] += __shfl_xor(ls2[i], off, 64);
        }
    }
    if (c == 0) {
        #pragma unroll
        for (int i = 0; i < 4; ++i) { red[w][g][i][0] = ls[i]; red[w][g][i][1] = ls2[i]; }
    }
    __syncthreads();

    // ---- finalize LN + store (all 16 rows valid: r = g*4+i) ----
    {
        float mu[4], rs[4];
        #pragma unroll
        for (int i = 0; i < 4; ++i) {
            float S = 0.f, S2 = 0.f;
            #pragma unroll
            for (int ww = 0; ww < 16; ++ww) { S += red[ww][g][i][0]; S2 += red[ww][g][i][1]; }
            mu[i] = S * (1.f / DIM);
            rs[i] = rsqrtf(S2 * (1.f / DIM) - mu[i] * mu[i] + 1e-5f);
        }
        #pragma unroll
        for (int nf = 0; nf < 4; ++nf) {
            const int d = w * 64 + nf * 16 + c;
            const float gv = gamma[d], bv = beta[d];
            #pragma unroll
            for (int i = 0; i < 4; ++i) {
                const int r = g * 4 + i;
                out[(size_t)(tok0 + r) * DIM + d] = (acc[nf][i] - mu[i]) * rs[i] * gv + bv;
            }
        }
    }
}

extern "C" void kernel_launch(void* const* d_in, const int* in_sizes, int n_in,
                              void* d_out, int out_size, void* d_ws, size_t ws_size,
                              hipStream_t stream) {
    const int*   smap  = (const int*)d_in[0];
    const float* table = (const float*)d_in[1];
    const float* gamma = (const float*)d_in[2];
    const float* beta  = (const float*)d_in[3];
    float*       out   = (float*)d_out;

    const int batches = in_sizes[0] / (IMG * IMG);       // = 2
    const int tokens  = batches * HPW * HPW;             // 2048
    const int ngrp    = tokens / TPB;                    // 128

    ushort* Tt2 = (ushort*)d_ws;                         // 512 KB
    ushort* Ab  = Tt2 + (size_t)64 * 4096;               // 1 MB ([grp][16][256])

    prep<<<64 + ngrp, 256, 0, stream>>>(smap, table, Tt2, Ab);
    gemm_ln<<<ngrp, NT2, 0, stream>>>(Ab, Tt2, gamma, beta, out);
}